// Round 10
// baseline (171.765 us; speedup 1.0000x reference)
//
#include <hip/hip_runtime.h>
#include <hip/hip_bf16.h>
#include <cstdint>

// LSTM cell: g[g,b,n] = sum_k A[b,k] * Wcat[g,k,n],  A = [x | h]  (K = 2048)
// i,f,o = sigmoid(g0,1,2), u = tanh(g3), c_t = i*u + f*c, h_t = o*tanh(c_t)
// Round 10: register-double-buffered K-loop. MFMA(t) consumes regs read LAST
// step; reads(t+1), stage(t+2) and MFMA(t) share one scheduling region (no
// lgkm0, no barrier between reads and MFMA -> compiler interleaves 1:1,
// AITER-style). One s_barrier + one vmcnt(0) (draining ~1-step-old loads)
// per K-step. Triple-buffered LDS (3 x 24KB), 2 blocks/CU.

#define LDS_TOTAL 73728     // 3 bufs x (A 8KB + B 16KB)

typedef __attribute__((ext_vector_type(8))) short bf16x8;    // 8 bf16 = 4 VGPR
typedef __attribute__((ext_vector_type(16))) float f32x16;   // 32x32 acc
typedef __attribute__((ext_vector_type(4))) unsigned int u32x4;

static __device__ __forceinline__ unsigned short f2bf(float f) {
  union { float f; unsigned int u; } v; v.f = f;
  unsigned int u = v.u;
  unsigned int r = (u + 0x7FFFu + ((u >> 16) & 1u)) >> 16;  // RTN-even
  return (unsigned short)r;
}

static __device__ __forceinline__ void load16(const void* gp, void* lp) {
  __builtin_amdgcn_global_load_lds(
      (const __attribute__((address_space(1))) void*)gp,
      (__attribute__((address_space(3))) void*)lp, 16, 0, 0);
}

static __device__ __forceinline__ float sigmoid_f(float x) {
  return 1.0f / (1.0f + __expf(-x));
}
static __device__ __forceinline__ float tanh_f(float x) {
  float e = __expf(-2.0f * fabsf(x));
  float r = (1.0f - e) / (1.0f + e);
  return copysignf(r, x);
}

// ---- prep 1: A = [x|h] -> k-chunked bf16: Ap[kblk 256][b 8192][8 elems] ----
__global__ __launch_bounds__(256) void pack_a_kernel(
    const float* __restrict__ x, const float* __restrict__ h,
    unsigned short* __restrict__ Ap) {
  __shared__ float tile[64][65];
  const int b0 = (blockIdx.x >> 5) << 6;
  const int k0 = (blockIdx.x & 31) << 6;
  const float* src; int ks;
  if (k0 < 1024) { src = x; ks = k0; } else { src = h; ks = k0 - 1024; }
  const int r = threadIdx.x >> 4;
  const int c4 = (threadIdx.x & 15) << 2;
  #pragma unroll
  for (int s = 0; s < 4; ++s) {
    float4 v = *(const float4*)(src + (size_t)(b0 + s * 16 + r) * 1024 + ks + c4);
    tile[s * 16 + r][c4 + 0] = v.x; tile[s * 16 + r][c4 + 1] = v.y;
    tile[s * 16 + r][c4 + 2] = v.z; tile[s * 16 + r][c4 + 3] = v.w;
  }
  __syncthreads();
  #pragma unroll
  for (int i = 0; i < 2; ++i) {
    int cc = i * 256 + threadIdx.x;
    int kb = cc >> 6, bb = cc & 63;
    union { unsigned short s[8]; u32x4 v; } o;
    #pragma unroll
    for (int e = 0; e < 8; ++e) o.s[e] = f2bf(tile[bb][kb * 8 + e]);
    *(u32x4*)(Ap + ((size_t)((k0 >> 3) + kb) * 8192 + b0 + bb) * 8) = o.v;
  }
}

// ---- prep 2: W -> k-chunked bf16: Wt2[kblk 256][g 4][n 1024][8 elems] ----
__global__ __launch_bounds__(256) void prep_w_kernel(
    const float* __restrict__ Wx, const float* __restrict__ Wh,
    unsigned short* __restrict__ Wt2) {
  __shared__ float tile[64][65];
  const int g = blockIdx.x >> 9;
  const int kt = (blockIdx.x >> 4) & 31;
  const int nt = blockIdx.x & 15;
  const int k0 = kt << 6, n0 = nt << 6;
  const float* W; int ks;
  if (k0 < 1024) { W = Wx + (size_t)g * 1048576; ks = k0; }
  else           { W = Wh + (size_t)g * 1048576; ks = k0 - 1024; }
  const int r = threadIdx.x >> 4;
  const int c4 = (threadIdx.x & 15) << 2;
  #pragma unroll
  for (int s = 0; s < 4; ++s) {
    float4 v = *(const float4*)(W + (size_t)(ks + s * 16 + r) * 1024 + n0 + c4);
    tile[s * 16 + r][c4 + 0] = v.x; tile[s * 16 + r][c4 + 1] = v.y;
    tile[s * 16 + r][c4 + 2] = v.z; tile[s * 16 + r][c4 + 3] = v.w;
  }
  __syncthreads();
  #pragma unroll
  for (int i = 0; i < 2; ++i) {
    int cc = i * 256 + threadIdx.x;
    int kb = cc >> 6, nn = cc & 63;
    union { unsigned short s[8]; u32x4 v; } o;
    #pragma unroll
    for (int e = 0; e < 8; ++e) o.s[e] = f2bf(tile[kb * 8 + e][nn]);
    *(u32x4*)(Wt2 + ((size_t)((k0 >> 3) + kb) * 4096 + g * 1024 + n0 + nn) * 8) = o.v;
  }
}

#define VMW(n) asm volatile("s_waitcnt vmcnt(" #n ")" ::: "memory")
#define BAR() __builtin_amdgcn_s_barrier()

// ---- main: fused 4-gate GEMM (32x32x16), reg-double-buffered K-loop ----
// 256 thr = 4 waves: wr = w>>1 (rows wr*64..+64), wc = w&1 (n wc*32..+32/gate).
// LDS buf 24KB: A[4 kblk][128 row][16B] @0, B[4 kblk][4 g][64 n][16B] @8192.
// 64 K-steps (BK=32). Step t region: VMW(0)+BAR, then {reads(t+1)->alt set,
// stage(t+2)->3rd buf, 16 MFMA(t) on current set} freely interleaved.
__global__ __launch_bounds__(256, 2) void lstm_gemm_kernel(
    const unsigned short* __restrict__ Ap,     // [256 kblk][8192 b][8]
    const unsigned short* __restrict__ Wt2,    // [256 kblk][4 g][1024 n][8]
    const float* __restrict__ cprev,
    float* __restrict__ out) {
  extern __shared__ char lds[];
  const int tid = threadIdx.x;
  const int l = tid & 63;
  const int w = tid >> 6;
  const int wr = w >> 1;               // 0..1
  const int wc = w & 1;                // 0..1
  const int bid = blockIdx.x;          // 1024 blocks
  const int xcd = bid & 7;             // nt-slab per XCD (W-slab L2-resident)
  const int cc = bid >> 3;             // 0..127
  const int nt = xcd * 2 + (cc >> 6);  // 16 n-tiles
  const int mt = cc & 63;              // 64 m-tiles
  const int m0 = mt << 7;              // BM = 128
  const int n0 = nt << 6;

  f32x16 acc[2][4];                    // [m-frag 32rows][gate]
  #pragma unroll
  for (int mf = 0; mf < 2; ++mf)
    #pragma unroll
    for (int g = 0; g < 4; ++g) acc[mf][g] = (f32x16)0.0f;

  const int ln = l & 31;
  const int hl = l >> 5;               // kblk parity within k16 slice

  // LDS read offsets (contiguous 512B per 32-lane group -> conflict-free)
  const int aOff = hl * 2048 + (wr * 64 + ln) * 16;          // +r*4096 +mf*512
  const int bOff = 8192 + hl * 4096 + (wc * 32 + ln) * 16;   // +r*8192 +g*1024

  // Stage bases. A: chunk c=j*256+tid -> kblk=(tid>>7)+2j, row=tid&127.
  const unsigned short* const gA =
      Ap + (size_t)((tid >> 7) * 8192 + m0 + (tid & 127)) * 8;
  // B: chunk c=j*256+tid -> kblk=j, g=(tid>>6)&3, n=tid&63.
  const unsigned short* const gB =
      Wt2 + (size_t)(((tid >> 6) & 3) * 1024 + n0 + (tid & 63)) * 8;
  const int dA = (tid & ~63) << 4;
  const int dB = 8192 + dA;

  auto stage = [&](int bo, int t) {     // 6 gload_lds (A 2, B 4)
    const unsigned short* a0 = gA + (size_t)t * 262144;   // t*4 kblk * 8192*8
    load16(a0,          lds + bo + dA);
    load16(a0 + 131072, lds + bo + dA + 4096);            // +2 kblk
    const unsigned short* b0 = gB + (size_t)t * 131072;   // t*4 kblk * 4096*8
    load16(b0,          lds + bo + dB);
    load16(b0 + 32768,  lds + bo + dB + 4096);            // +1 kblk
    load16(b0 + 65536,  lds + bo + dB + 8192);
    load16(b0 + 98304,  lds + bo + dB + 12288);
  };

  bf16x8 eA[2][2], eB[2][4], oA[2][2], oB[2][4];  // even/odd reg sets

#define RD_SET(SA, SB, bo) do {                                   \
    const char* base_ = lds + (bo);                               \
    SA[0][0] = *(const bf16x8*)(base_ + aOff);                    \
    SA[0][1] = *(const bf16x8*)(base_ + aOff + 512);              \
    SA[1][0] = *(const bf16x8*)(base_ + aOff + 4096);             \
    SA[1][1] = *(const bf16x8*)(base_ + aOff + 4608);             \
    SB[0][0] = *(const bf16x8*)(base_ + bOff);                    \
    SB[0][1] = *(const bf16x8*)(base_ + bOff + 1024);             \
    SB[0][2] = *(const bf16x8*)(base_ + bOff + 2048);             \
    SB[0][3] = *(const bf16x8*)(base_ + bOff + 3072);             \
    SB[1][0] = *(const bf16x8*)(base_ + bOff + 8192);             \
    SB[1][1] = *(const bf16x8*)(base_ + bOff + 9216);             \
    SB[1][2] = *(const bf16x8*)(base_ + bOff + 10240);            \
    SB[1][3] = *(const bf16x8*)(base_ + bOff + 11264);            \
  } while (0)

#define MM_SET(SA, SB) do {                                       \
    _Pragma("unroll")                                             \
    for (int r_ = 0; r_ < 2; ++r_)                                \
      _Pragma("unroll")                                           \
      for (int mf_ = 0; mf_ < 2; ++mf_)                           \
        _Pragma("unroll")                                         \
        for (int g_ = 0; g_ < 4; ++g_)                            \
          acc[mf_][g_] = __builtin_amdgcn_mfma_f32_32x32x16_bf16( \
              SA[r_][mf_], SB[r_][g_], acc[mf_][g_], 0, 0, 0);    \
  } while (0)

  // Prologue: stage(0)->buf0, stage(1)->buf1; drain stage(0); reads(0)->E.
  int bo0 = 0, bo1 = 24576, bo2 = 49152;
  stage(bo0, 0);
  stage(bo1, 1);
  VMW(6);
  BAR();
  RD_SET(eA, eB, bo0);

  #pragma unroll 1
  for (int tt = 0; tt < 31; ++tt) {
    const int t = 2 * tt;
    // even step t: MFMA on E, reads(t+1)->O, stage(t+2)
    VMW(0); BAR();
    RD_SET(oA, oB, bo1);
    stage(bo2, t + 2);
    MM_SET(eA, eB);
    { int tmp = bo0; bo0 = bo1; bo1 = bo2; bo2 = tmp; }
    // odd step t+1: MFMA on O, reads(t+2)->E, stage(t+3)
    VMW(0); BAR();
    RD_SET(eA, eB, bo1);
    stage(bo2, t + 3);
    MM_SET(oA, oB);
    { int tmp = bo0; bo0 = bo1; bo1 = bo2; bo2 = tmp; }
  }
  // t = 62: no stage(64)
  VMW(0); BAR();
  RD_SET(oA, oB, bo1);
  MM_SET(eA, eB);
  // t = 63: no reads, no stage
  BAR();
  MM_SET(oA, oB);

  // Epilogue: 32x32 C/D layout col = lane&31, row = (r&3)+8*(r>>2)+4*(l>>5)
  const int colB = n0 + wc * 32 + ln;
  #pragma unroll
  for (int mf = 0; mf < 2; ++mf) {
    #pragma unroll
    for (int r = 0; r < 16; ++r) {
      int row = m0 + wr * 64 + mf * 32 + (r & 3) + ((r >> 2) << 3) + (hl << 2);
      float gi = acc[mf][0][r];
      float gf = acc[mf][1][r];
      float go = acc[mf][2][r];
      float gu = acc[mf][3][r];
      float i_ = sigmoid_f(gi);
      float f_ = sigmoid_f(gf);
      float o_ = sigmoid_f(go);
      float u_ = tanh_f(gu);
      size_t idx = (size_t)row * 1024 + colB;
      float ct = i_ * u_ + f_ * cprev[idx];
      float ht = o_ * tanh_f(ct);
      out[idx] = ht;                   // h_t
      out[8388608 + idx] = ct;         // c_t
    }
  }
#undef RD_SET
#undef MM_SET
}

extern "C" void kernel_launch(void* const* d_in, const int* in_sizes, int n_in,
                              void* d_out, int out_size, void* d_ws, size_t ws_size,
                              hipStream_t stream) {
  const float* x  = (const float*)d_in[0];
  const float* h  = (const float*)d_in[1];
  const float* c  = (const float*)d_in[2];
  const float* Wx = (const float*)d_in[3];
  const float* Wh = (const float*)d_in[4];
  float* out = (float*)d_out;

  unsigned short* Ap  = (unsigned short*)d_ws;                   // 33,554,432 B
  unsigned short* Wt2 = (unsigned short*)((char*)d_ws + 33554432); // 16,777,216 B

  hipFuncSetAttribute((const void*)lstm_gemm_kernel,
                      hipFuncAttributeMaxDynamicSharedMemorySize, LDS_TOTAL);

  pack_a_kernel<<<4096, 256, 0, stream>>>(x, h, Ap);
  prep_w_kernel<<<2048, 256, 0, stream>>>(Wx, Wh, Wt2);
  lstm_gemm_kernel<<<dim3(1024), dim3(256), LDS_TOTAL, stream>>>(Ap, Wt2, c, out);
}